// Round 11
// baseline (549.833 us; speedup 1.0000x reference)
//
#include <hip/hip_runtime.h>
#include <type_traits>

// LSTMNet: B=1024, T=2048, H=64, NC=10, input_size=1.
// R23: R22 (best, 521us rocprof) + ONE change: the hot-loop step barrier is
// now inline-asm "s_waitcnt lgkmcnt(0); s_barrier" instead of __syncthreads().
// Why: compiler emits s_waitcnt vmcnt(0) lgkmcnt(0) before s_barrier, but the
// step exchange only requires lgkmcnt(0) (h ds_write visibility). vmcnt(0)
// forces each step-barrier after a prefetch issue to drain the in-flight HBM
// x-load (~300cy exposed x 16 boundaries) and couples global traffic into
// every step. lgkm-only barrier decouples it. sched_barrier(0) after the asm
// prevents any scheduler motion across it (rule-18 belt and braces; the LDS
// consumers are memory ops, ordered by the "memory" clobber).
// Boundary (tl==0) and epilogue barriers remain full __syncthreads().
// L model (calibrated): 612cy = ~130 ds_read + ~250-300 solo-wave MFMA issue
// (8/wave forced: 256 gate-outputs / 4 waves / K-split) + ~70-100 update
// chain + ~90 write/barrier. All structural alternatives measured/modeled
// worse (R13 2-pass, R15 2-blk/CU, R21 in-wave x2, kt/gate-split need 2nd
// barrier, row-packing neutral since time = 2048 x L).
// Precision: bit-identical math to R20/R22 (absmax 9.77e-4 measured).

#define T_STEPS 2048
#define HID 64
#define NCLS 10
#define XCH 128   // x chunk length (steps)
#define ROWS 4    // batch rows per block

#define KQS 40    // kq stride in shorts (80B = 20 banks, 16B-aligned)
#define KTS 168   // kt stride in shorts (4*KQS + 8 pad; 336B, 16B-aligned)

typedef short bf16x8 __attribute__((ext_vector_type(8)));
typedef float f32x4 __attribute__((ext_vector_type(4)));

__device__ __forceinline__ unsigned short f2bf(float f) {  // RNE f32->bf16
    unsigned u = __builtin_bit_cast(unsigned, f);
    u = u + 0x7FFFu + ((u >> 16) & 1u);
    return (unsigned short)(u >> 16);
}

// step barrier: LDS-visibility only (no vmcnt drain)
__device__ __forceinline__ void lgkm_barrier() {
    asm volatile("s_waitcnt lgkmcnt(0)\n\ts_barrier" ::: "memory");
    __builtin_amdgcn_sched_barrier(0);
}

__global__ __attribute__((amdgpu_flat_work_group_size(256, 256),
                          amdgpu_waves_per_eu(1, 1)))
void lstm_mfma_kernel(
    const float* __restrict__ x,      // [B, 1, T]
    const float* __restrict__ W_ih,   // [256, 1]
    const float* __restrict__ W_hh,   // [256, 64]
    const float* __restrict__ b_ih,   // [256]
    const float* __restrict__ b_hh,   // [256]
    const float* __restrict__ fc1_w,  // [64, 64]
    const float* __restrict__ fc1_b,  // [64]
    const float* __restrict__ fc2_w,  // [10, 64]
    const float* __restrict__ fc2_b,  // [10]
    float* __restrict__ out)          // [B, 10]
{
    const int tid  = threadIdx.x;
    const int lane = tid & 63;
    const int w    = tid >> 6;        // wave id = unit-chunk owner
    const int quad = lane >> 4;       // = batch row within block (D-row 4*quad)
    const int col  = lane & 15;
    const int row0 = blockIdx.x * ROWS;

    const float L2E = 1.4426950408889634f;

    // ---- LDS union: 32KB staging (dead after B-frag load) overlaps runtime ----
    __shared__ __align__(16) char smem[32768];
    short* whi = (short*)smem;                 // staging [0,32768)
    // runtime (valid only after the staging->register handoff sync):
    short (*abuf)[2 * KTS]     = (short(*)[2 * KTS])smem;           // 1344 B
    float (*xlds)[XCH + 4]     = (float(*)[XCH + 4])(smem + 1344);  // 2112 B
    float (*hf)[HID + 1]       = (float(*)[HID + 1])(smem + 3456);  // 1040 B
    float (*r1buf)[HID + 1]    = (float(*)[HID + 1])(smem + 4496);  // 1040 B

    // ---- stage: W_hh f32 -> bf16 fragments, pre-scaled per gate ----
    // tile t_ = g*4 + u4  => wave w (reading t_ = gg*4 + w) gets all 4 gates
    // for units 16w..16w+15.
    for (int idx = tid; idx < 256 * 64; idx += 256) {
        int r_ = idx >> 6;            // gate-major row 0..255
        int k  = idx & 63;
        int g = r_ >> 6, u = r_ & 63;
        float scg = (g == 2) ? -2.0f * L2E : -L2E;
        float f = W_hh[r_ * 64 + k] * scg;
        int u4 = u >> 4, n = u & 15;
        int kt = k >> 5, kq = (k & 31) >> 3, j = k & 7;
        int off = (((g * 4 + u4) * 2 + kt) * 64 + (kq * 16 + n)) * 8 + j;
        whi[off] = (short)f2bf(f);
    }
    __syncthreads();

    // ---- B fragments -> registers (wave w: tiles t_ = gg*4 + w) ----
    const int u0 = w * 16 + col;      // this lane's unit (cols of all 4 tiles)
    bf16x8 Bq[4][2];
    f32x4 biasC[4];
    f32x4 zerov = {0.f, 0.f, 0.f, 0.f};
    #pragma unroll
    for (int gg = 0; gg < 4; ++gg) {
        int t_ = gg * 4 + w;
        #pragma unroll
        for (int kt = 0; kt < 2; ++kt) {
            int off = ((t_ * 2 + kt) * 64 + lane) * 8;
            Bq[gg][kt] = *(const bf16x8*)&whi[off];
            asm volatile("" : "+v"(Bq[gg][kt]));
        }
        float scg = (gg == 2) ? -2.0f * L2E : -L2E;
        float bs = (b_ih[gg * HID + u0] + b_hh[gg * HID + u0]) * scg;
        #pragma unroll
        for (int r = 0; r < 4; ++r) biasC[gg][r] = bs;
    }
    __syncthreads();   // all waves done READING staging; smem may be reused now

    // zero BOTH A buffers (h0 = 0)
    for (int idx = tid; idx < 2 * 2 * KTS; idx += 256) ((short*)abuf)[idx] = 0;

    // ---- update constants: quad q owns cell (batch row q, unit u0) ----
    float wih_u[4];
    #pragma unroll
    for (int gg = 0; gg < 4; ++gg) {
        float scg = (gg == 2) ? -2.0f * L2E : -L2E;
        wih_u[gg] = W_ih[gg * HID + u0] * scg;
    }
    float cc = 0.f, hl = 0.f;

    // invariant LDS coords (compact layout)
    // read: lane l -> kq = l>>4, row' = (l>>2)&3 (valid for A-rows 4*row';
    //        other lanes alias -> garbage D rows, never read)
    const int ard0 = (lane >> 4) * KQS + ((lane >> 2) & 3) * 8;   // kt1 at +KTS
    // write: h(batch quad, unit u0) at (kt=u0>>5, kq=(u0>>3)&3, q=quad, j=u0&7)
    const int awr  = (u0 >> 5) * KTS + ((u0 >> 3) & 3) * KQS + quad * 8 + (u0 & 7);

    const float* xbase = x + (size_t)row0 * T_STEPS;

    // prime x prefetch for chunk 0 (loads issue here, consumed at tc=0)
    float pf0, pf1;
    {
        const float* src = xbase + (size_t)w * T_STEPS;
        pf0 = src[lane];
        pf1 = src[lane + 64];
    }
    __syncthreads();   // abuf zeroed

    auto step = [&](auto cur_c, float xv) __attribute__((always_inline)) {
        constexpr int CUR = decltype(cur_c)::value;
        constexpr int NXT = CUR ^ 1;

        // ---- all 4 gates for units 16w..16w+15, rows {0,4,8,12} ----
        bf16x8 A0 = *(const bf16x8*)&abuf[CUR][ard0];
        bf16x8 A1 = *(const bf16x8*)&abuf[CUR][ard0 + KTS];

        // kt-parallel: two independent MFMAs, combine reg0 with one add
        // (R16 source order: all lo, then all hi; gate order i,f,g,o)
        f32x4 alo[4], ahi[4];
        #pragma unroll
        for (int gg = 0; gg < 4; ++gg)
            alo[gg] = __builtin_amdgcn_mfma_f32_16x16x32_bf16(A0, Bq[gg][0], biasC[gg], 0, 0, 0);
        #pragma unroll
        for (int gg = 0; gg < 4; ++gg)
            ahi[gg] = __builtin_amdgcn_mfma_f32_16x16x32_bf16(A1, Bq[gg][1], zerov, 0, 0, 0);

        // ---- fused update: quad q -> D-row 4q (reg0), ALL 64 lanes active ----
        {
            // pre-scaled args: sigm gates hold -log2e*a, tanh gate -2log2e*a
            float a0 = fmaf(xv, wih_u[0], alo[0][0] + ahi[0][0]);
            float a1 = fmaf(xv, wih_u[1], alo[1][0] + ahi[1][0]);
            float a2 = fmaf(xv, wih_u[2], alo[2][0] + ahi[2][0]);
            float a3 = fmaf(xv, wih_u[3], alo[3][0] + ahi[3][0]);
            float ig = __builtin_amdgcn_rcpf(1.0f + __builtin_amdgcn_exp2f(a0));
            float fg = __builtin_amdgcn_rcpf(1.0f + __builtin_amdgcn_exp2f(a1));
            float gv = fmaf(2.0f, __builtin_amdgcn_rcpf(1.0f + __builtin_amdgcn_exp2f(a2)), -1.0f);
            float og = __builtin_amdgcn_rcpf(1.0f + __builtin_amdgcn_exp2f(a3));
            cc = fmaf(fg, cc, ig * gv);
            float ec = __builtin_amdgcn_exp2f(-2.8853900817779268f * cc);
            float th = fmaf(2.0f, __builtin_amdgcn_rcpf(1.0f + ec), -1.0f);
            hl = og * th;
            unsigned hp;
            asm("v_cvt_pk_bf16_f32 %0, %1, %2" : "=v"(hp) : "v"(hl), "v"(hl));
            abuf[NXT][awr] = (short)hp;
        }
        lgkm_barrier();   // h-frags visible; NO vmcnt drain (prefetch floats)
    };

    #pragma unroll 1
    for (int tc = 0; tc < T_STEPS; tc += 2) {
        const int tl = tc & (XCH - 1);
        if (tl == 0) {
            // boundary: commit prefetched chunk to LDS, then issue next loads
            xlds[w][lane]      = pf0;
            xlds[w][lane + 64] = pf1;
            __syncthreads();   // full barrier at chunk boundary (16x total)
            int nc = (tc + XCH < T_STEPS) ? (tc + XCH) : tc;  // clamp; tail unused
            const float* src = xbase + (size_t)w * T_STEPS + nc;
            pf0 = src[lane];
            pf1 = src[lane + 64];
        }
        // hoist both steps' x reads (issue with/before A-reads; consumed late)
        float xv0 = xlds[quad][tl];
        float xv1 = xlds[quad][tl + 1];
        step(std::integral_constant<int, 0>{}, xv0);  // reads abuf[0], writes abuf[1]
        step(std::integral_constant<int, 1>{}, xv1);  // reads abuf[1], writes abuf[0]
    }

    // ---- epilogue: gather h, fc1 (relu) + fc2 ----
    hf[quad][u0] = hl;   // (row quad, unit 16w+col): 4x64 values, all lanes
    __syncthreads();

    if (w < ROWS) {
        // thread -> (row = w, unit = lane)
        float s = fc1_b[lane];
        const float4* wrow = (const float4*)(fc1_w + lane * HID);
        #pragma unroll
        for (int j4 = 0; j4 < HID / 4; ++j4) {
            float4 wv = wrow[j4];
            s = fmaf(hf[w][j4 * 4 + 0], wv.x, s);
            s = fmaf(hf[w][j4 * 4 + 1], wv.y, s);
            s = fmaf(hf[w][j4 * 4 + 2], wv.z, s);
            s = fmaf(hf[w][j4 * 4 + 3], wv.w, s);
        }
        r1buf[w][lane] = fmaxf(s, 0.0f);
    }
    __syncthreads();

    if (tid < ROWS * NCLS) {
        int m = tid / NCLS, cls = tid % NCLS;
        float s = fc2_b[cls];
        const float* w2 = fc2_w + cls * HID;
        #pragma unroll
        for (int j = 0; j < HID; ++j) s = fmaf(r1buf[m][j], w2[j], s);
        out[(size_t)(row0 + m) * NCLS + cls] = s;
    }
}

extern "C" void kernel_launch(void* const* d_in, const int* in_sizes, int n_in,
                              void* d_out, int out_size, void* d_ws, size_t ws_size,
                              hipStream_t stream) {
    const float* x     = (const float*)d_in[0];
    const float* W_ih  = (const float*)d_in[1];
    const float* W_hh  = (const float*)d_in[2];
    const float* b_ih  = (const float*)d_in[3];
    const float* b_hh  = (const float*)d_in[4];
    const float* fc1_w = (const float*)d_in[5];
    const float* fc1_b = (const float*)d_in[6];
    const float* fc2_w = (const float*)d_in[7];
    const float* fc2_b = (const float*)d_in[8];
    float* out = (float*)d_out;

    dim3 grid(256);   // 1024 rows / 4 rows per block -> 1 block per CU
    dim3 block(256);  // 4 waves (1 per SIMD)
    lstm_mfma_kernel<<<grid, block, 0, stream>>>(x, W_ih, W_hh, b_ih, b_hh,
                                                 fc1_w, fc1_b, fc2_w, fc2_b, out);
}

// Round 12
// 544.725 us; speedup vs baseline: 1.0094x; 1.0094x over previous
//
#include <hip/hip_runtime.h>
#include <type_traits>

// LSTMNet: B=1024, T=2048, H=64, NC=10, input_size=1.
// R24: exact revert to R22 (best measured: 521us rocprof / 541 harness).
// R23's lgkm-only step barrier + sched_barrier(0) was -13us: the vmcnt(0)
// drain it removed costs ~5cy/step amortized (one drain per 64-step chunk),
// while sched_barrier(0) blocked cross-barrier scheduling. Third confirmed
// loss from hand-constraining the scheduler (SGB -50, R17 reorder -12,
// R23 -13): compiler's free schedule wins on this codegen.
// Session floor model (calibrated R13-R23): L ~= 610cy/step =
//   ~130 ds_read + ~250-300 solo-wave MFMA issue (8/wave forced:
//   256 gate-outputs / 4 waves / K=32) + ~100 update chain + ~90 barrier.
// Structural alternatives all measured/modeled worse; i8 K=64 breaks the
// absmax budget. Latency-bound by the recurrence, not a throughput roofline.
// Structure: 256 blocks x 4 waves, ROWS=4 (quad q = batch row q -> D-row 4q
// reg0), fused gate+update, 1 barrier + 1 LDS round trip/step, compact 4-row
// A-exchange layout (conflicts 1.72e7 -> 3.95e5), waves_per_eu(1,1),
// x-chunk register prefetch, hoisted xv reads.
// Precision: bit-identical math to R20/R22 (absmax 9.77e-4 measured).

#define T_STEPS 2048
#define HID 64
#define NCLS 10
#define XCH 128   // x chunk length (steps)
#define ROWS 4    // batch rows per block

#define KQS 40    // kq stride in shorts (80B = 20 banks, 16B-aligned)
#define KTS 168   // kt stride in shorts (4*KQS + 8 pad; 336B, 16B-aligned)

typedef short bf16x8 __attribute__((ext_vector_type(8)));
typedef float f32x4 __attribute__((ext_vector_type(4)));

__device__ __forceinline__ unsigned short f2bf(float f) {  // RNE f32->bf16
    unsigned u = __builtin_bit_cast(unsigned, f);
    u = u + 0x7FFFu + ((u >> 16) & 1u);
    return (unsigned short)(u >> 16);
}

__global__ __attribute__((amdgpu_flat_work_group_size(256, 256),
                          amdgpu_waves_per_eu(1, 1)))
void lstm_mfma_kernel(
    const float* __restrict__ x,      // [B, 1, T]
    const float* __restrict__ W_ih,   // [256, 1]
    const float* __restrict__ W_hh,   // [256, 64]
    const float* __restrict__ b_ih,   // [256]
    const float* __restrict__ b_hh,   // [256]
    const float* __restrict__ fc1_w,  // [64, 64]
    const float* __restrict__ fc1_b,  // [64]
    const float* __restrict__ fc2_w,  // [10, 64]
    const float* __restrict__ fc2_b,  // [10]
    float* __restrict__ out)          // [B, 10]
{
    const int tid  = threadIdx.x;
    const int lane = tid & 63;
    const int w    = tid >> 6;        // wave id = unit-chunk owner
    const int quad = lane >> 4;       // = batch row within block (D-row 4*quad)
    const int col  = lane & 15;
    const int row0 = blockIdx.x * ROWS;

    const float L2E = 1.4426950408889634f;

    // ---- LDS union: 32KB staging (dead after B-frag load) overlaps runtime ----
    __shared__ __align__(16) char smem[32768];
    short* whi = (short*)smem;                 // staging [0,32768)
    // runtime (valid only after the staging->register handoff sync):
    short (*abuf)[2 * KTS]     = (short(*)[2 * KTS])smem;           // 1344 B
    float (*xlds)[XCH + 4]     = (float(*)[XCH + 4])(smem + 1344);  // 2112 B
    float (*hf)[HID + 1]       = (float(*)[HID + 1])(smem + 3456);  // 1040 B
    float (*r1buf)[HID + 1]    = (float(*)[HID + 1])(smem + 4496);  // 1040 B

    // ---- stage: W_hh f32 -> bf16 fragments, pre-scaled per gate ----
    // tile t_ = g*4 + u4  => wave w (reading t_ = gg*4 + w) gets all 4 gates
    // for units 16w..16w+15.
    for (int idx = tid; idx < 256 * 64; idx += 256) {
        int r_ = idx >> 6;            // gate-major row 0..255
        int k  = idx & 63;
        int g = r_ >> 6, u = r_ & 63;
        float scg = (g == 2) ? -2.0f * L2E : -L2E;
        float f = W_hh[r_ * 64 + k] * scg;
        int u4 = u >> 4, n = u & 15;
        int kt = k >> 5, kq = (k & 31) >> 3, j = k & 7;
        int off = (((g * 4 + u4) * 2 + kt) * 64 + (kq * 16 + n)) * 8 + j;
        whi[off] = (short)f2bf(f);
    }
    __syncthreads();

    // ---- B fragments -> registers (wave w: tiles t_ = gg*4 + w) ----
    const int u0 = w * 16 + col;      // this lane's unit (cols of all 4 tiles)
    bf16x8 Bq[4][2];
    f32x4 biasC[4];
    f32x4 zerov = {0.f, 0.f, 0.f, 0.f};
    #pragma unroll
    for (int gg = 0; gg < 4; ++gg) {
        int t_ = gg * 4 + w;
        #pragma unroll
        for (int kt = 0; kt < 2; ++kt) {
            int off = ((t_ * 2 + kt) * 64 + lane) * 8;
            Bq[gg][kt] = *(const bf16x8*)&whi[off];
            asm volatile("" : "+v"(Bq[gg][kt]));
        }
        float scg = (gg == 2) ? -2.0f * L2E : -L2E;
        float bs = (b_ih[gg * HID + u0] + b_hh[gg * HID + u0]) * scg;
        #pragma unroll
        for (int r = 0; r < 4; ++r) biasC[gg][r] = bs;
    }
    __syncthreads();   // all waves done READING staging; smem may be reused now

    // zero BOTH A buffers (h0 = 0)
    for (int idx = tid; idx < 2 * 2 * KTS; idx += 256) ((short*)abuf)[idx] = 0;

    // ---- update constants: quad q owns cell (batch row q, unit u0) ----
    float wih_u[4];
    #pragma unroll
    for (int gg = 0; gg < 4; ++gg) {
        float scg = (gg == 2) ? -2.0f * L2E : -L2E;
        wih_u[gg] = W_ih[gg * HID + u0] * scg;
    }
    float cc = 0.f, hl = 0.f;

    // invariant LDS coords (compact layout)
    // read: lane l -> kq = l>>4, row' = (l>>2)&3 (valid for A-rows 4*row';
    //        other lanes alias -> garbage D rows, never read)
    const int ard0 = (lane >> 4) * KQS + ((lane >> 2) & 3) * 8;   // kt1 at +KTS
    // write: h(batch quad, unit u0) at (kt=u0>>5, kq=(u0>>3)&3, q=quad, j=u0&7)
    const int awr  = (u0 >> 5) * KTS + ((u0 >> 3) & 3) * KQS + quad * 8 + (u0 & 7);

    const float* xbase = x + (size_t)row0 * T_STEPS;

    // prime x prefetch for chunk 0 (loads issue here, consumed at tc=0)
    float pf0, pf1;
    {
        const float* src = xbase + (size_t)w * T_STEPS;
        pf0 = src[lane];
        pf1 = src[lane + 64];
    }
    __syncthreads();   // abuf zeroed

    auto step = [&](auto cur_c, float xv) __attribute__((always_inline)) {
        constexpr int CUR = decltype(cur_c)::value;
        constexpr int NXT = CUR ^ 1;

        // ---- all 4 gates for units 16w..16w+15, rows {0,4,8,12} ----
        bf16x8 A0 = *(const bf16x8*)&abuf[CUR][ard0];
        bf16x8 A1 = *(const bf16x8*)&abuf[CUR][ard0 + KTS];

        // kt-parallel: two independent MFMAs, combine reg0 with one add
        // (R16 source order: all lo, then all hi; gate order i,f,g,o)
        f32x4 alo[4], ahi[4];
        #pragma unroll
        for (int gg = 0; gg < 4; ++gg)
            alo[gg] = __builtin_amdgcn_mfma_f32_16x16x32_bf16(A0, Bq[gg][0], biasC[gg], 0, 0, 0);
        #pragma unroll
        for (int gg = 0; gg < 4; ++gg)
            ahi[gg] = __builtin_amdgcn_mfma_f32_16x16x32_bf16(A1, Bq[gg][1], zerov, 0, 0, 0);

        // ---- fused update: quad q -> D-row 4q (reg0), ALL 64 lanes active ----
        {
            // pre-scaled args: sigm gates hold -log2e*a, tanh gate -2log2e*a
            float a0 = fmaf(xv, wih_u[0], alo[0][0] + ahi[0][0]);
            float a1 = fmaf(xv, wih_u[1], alo[1][0] + ahi[1][0]);
            float a2 = fmaf(xv, wih_u[2], alo[2][0] + ahi[2][0]);
            float a3 = fmaf(xv, wih_u[3], alo[3][0] + ahi[3][0]);
            float ig = __builtin_amdgcn_rcpf(1.0f + __builtin_amdgcn_exp2f(a0));
            float fg = __builtin_amdgcn_rcpf(1.0f + __builtin_amdgcn_exp2f(a1));
            float gv = fmaf(2.0f, __builtin_amdgcn_rcpf(1.0f + __builtin_amdgcn_exp2f(a2)), -1.0f);
            float og = __builtin_amdgcn_rcpf(1.0f + __builtin_amdgcn_exp2f(a3));
            cc = fmaf(fg, cc, ig * gv);
            float ec = __builtin_amdgcn_exp2f(-2.8853900817779268f * cc);
            float th = fmaf(2.0f, __builtin_amdgcn_rcpf(1.0f + ec), -1.0f);
            hl = og * th;
            unsigned hp;
            asm("v_cvt_pk_bf16_f32 %0, %1, %2" : "=v"(hp) : "v"(hl), "v"(hl));
            abuf[NXT][awr] = (short)hp;
        }
        __syncthreads();   // new h-frags visible (single barrier per step)
    };

    #pragma unroll 1
    for (int tc = 0; tc < T_STEPS; tc += 2) {
        const int tl = tc & (XCH - 1);
        if (tl == 0) {
            // boundary: commit prefetched chunk to LDS, then issue next loads
            xlds[w][lane]      = pf0;
            xlds[w][lane + 64] = pf1;
            __syncthreads();
            int nc = (tc + XCH < T_STEPS) ? (tc + XCH) : tc;  // clamp; tail unused
            const float* src = xbase + (size_t)w * T_STEPS + nc;
            pf0 = src[lane];
            pf1 = src[lane + 64];
        }
        // hoist both steps' x reads (issue with/before A-reads; consumed late)
        float xv0 = xlds[quad][tl];
        float xv1 = xlds[quad][tl + 1];
        step(std::integral_constant<int, 0>{}, xv0);  // reads abuf[0], writes abuf[1]
        step(std::integral_constant<int, 1>{}, xv1);  // reads abuf[1], writes abuf[0]
    }

    // ---- epilogue: gather h, fc1 (relu) + fc2 ----
    hf[quad][u0] = hl;   // (row quad, unit 16w+col): 4x64 values, all lanes
    __syncthreads();

    if (w < ROWS) {
        // thread -> (row = w, unit = lane)
        float s = fc1_b[lane];
        const float4* wrow = (const float4*)(fc1_w + lane * HID);
        #pragma unroll
        for (int j4 = 0; j4 < HID / 4; ++j4) {
            float4 wv = wrow[j4];
            s = fmaf(hf[w][j4 * 4 + 0], wv.x, s);
            s = fmaf(hf[w][j4 * 4 + 1], wv.y, s);
            s = fmaf(hf[w][j4 * 4 + 2], wv.z, s);
            s = fmaf(hf[w][j4 * 4 + 3], wv.w, s);
        }
        r1buf[w][lane] = fmaxf(s, 0.0f);
    }
    __syncthreads();

    if (tid < ROWS * NCLS) {
        int m = tid / NCLS, cls = tid % NCLS;
        float s = fc2_b[cls];
        const float* w2 = fc2_w + cls * HID;
        #pragma unroll
        for (int j = 0; j < HID; ++j) s = fmaf(r1buf[m][j], w2[j], s);
        out[(size_t)(row0 + m) * NCLS + cls] = s;
    }
}

extern "C" void kernel_launch(void* const* d_in, const int* in_sizes, int n_in,
                              void* d_out, int out_size, void* d_ws, size_t ws_size,
                              hipStream_t stream) {
    const float* x     = (const float*)d_in[0];
    const float* W_ih  = (const float*)d_in[1];
    const float* W_hh  = (const float*)d_in[2];
    const float* b_ih  = (const float*)d_in[3];
    const float* b_hh  = (const float*)d_in[4];
    const float* fc1_w = (const float*)d_in[5];
    const float* fc1_b = (const float*)d_in[6];
    const float* fc2_w = (const float*)d_in[7];
    const float* fc2_b = (const float*)d_in[8];
    float* out = (float*)d_out;

    dim3 grid(256);   // 1024 rows / 4 rows per block -> 1 block per CU
    dim3 block(256);  // 4 waves (1 per SIMD)
    lstm_mfma_kernel<<<grid, block, 0, stream>>>(x, W_ih, W_hh, b_ih, b_hh,
                                                 fc1_w, fc1_b, fc2_w, fc2_b, out);
}

// Round 13
// 508.623 us; speedup vs baseline: 1.0810x; 1.0710x over previous
//
#include <hip/hip_runtime.h>
#include <type_traits>

// LSTMNet: B=1024, T=2048, H=64, NC=10, input_size=1.
// R25: i8 K=64 MFMA experiment. The bf16 structure's MFMA count is provably
// minimal (N*K needed per wave-step = 64 units x K=64 = 4096; bf16 MFMA
// supplies 512 -> 8 forced). mfma_i32_16x16x64_i8 supplies 1024 -> 4 MFMAs,
// and the A-frag is ONE ds_read_b128 (16B = K=64 i8). Attacks the two
// largest L segments: MFMA ~250-300cy -> ~125-150, ds_read 2->1.
// Quantization: h at fixed scale 127 (|h|<1); W_hh per-row i8 (row max/127),
// i32 accumulation exact; dequant folded into one fma per gate:
//   a = fmaf((float)dot, dqs, fmaf(xv, wih_s, bxc))  [all scg-pre-scaled]
// DECLARED RISKS: (1) absmax predicted 2-4e-3 vs ~3.1e-3 threshold;
// (2) i8 A/B fragment mapping assumed = bf16 pattern extended (16
// K-contiguous vals per lane, chunk = lane>>4). Revert path = R24 (521us).
// Structure otherwise identical to R22/R24: 256 blocks x 4 waves, ROWS=4,
// quad q = batch row q -> D-row 4q reg0, fused update, 1 barrier/step,
// waves_per_eu(1,1), x-chunk register prefetch, hoisted xv reads.

#define T_STEPS 2048
#define HID 64
#define NCLS 10
#define XCH 128   // x chunk length (steps)
#define ROWS 4    // batch rows per block

typedef int   i32x4 __attribute__((ext_vector_type(4)));
typedef float f32x4 __attribute__((ext_vector_type(4)));

__global__ __attribute__((amdgpu_flat_work_group_size(256, 256),
                          amdgpu_waves_per_eu(1, 1)))
void lstm_mfma_kernel(
    const float* __restrict__ x,      // [B, 1, T]
    const float* __restrict__ W_ih,   // [256, 1]
    const float* __restrict__ W_hh,   // [256, 64]
    const float* __restrict__ b_ih,   // [256]
    const float* __restrict__ b_hh,   // [256]
    const float* __restrict__ fc1_w,  // [64, 64]
    const float* __restrict__ fc1_b,  // [64]
    const float* __restrict__ fc2_w,  // [10, 64]
    const float* __restrict__ fc2_b,  // [10]
    float* __restrict__ out)          // [B, 10]
{
    const int tid  = threadIdx.x;
    const int lane = tid & 63;
    const int w    = tid >> 6;        // wave id = unit-chunk owner
    const int quad = lane >> 4;       // = batch row within block (D-row 4*quad)
    const int col  = lane & 15;
    const int row0 = blockIdx.x * ROWS;

    const float L2E = 1.4426950408889634f;

    // ---- LDS union: 17KB staging (dead after B-frag load) overlaps runtime ----
    __shared__ __align__(16) char smem[32768];
    char*  wq8 = smem;                        // staging Wq [0, 16384)
    float* scl = (float*)(smem + 16384);      // per-row m/127^2 [16384,17408)
    // runtime (valid only after the staging->register handoff sync):
    char  (*hbuf)[256]      = (char(*)[256])smem;               //  512 B
    float (*xlds)[XCH + 4]  = (float(*)[XCH + 4])(smem + 512);  // 2112 B
    float (*hf)[HID + 1]    = (float(*)[HID + 1])(smem + 2624); // 1040 B
    float (*r1buf)[HID + 1] = (float(*)[HID + 1])(smem + 3664); // 1040 B

    // ---- stage: W_hh -> per-row i8 (row = gate-major 0..255, one/thread) ----
    // Wq layout: off = t_*1024 + kc*256 + n*16 + j
    //   t_ = g*4 + (u>>4) (16x16 col-tile), kc = k>>4, n = u&15, j = k&15.
    // B-frag read (wave w, gate gg): lane l reads 16B at
    //   ((gg*4+w)*4 + (l>>4))*256 + (l&15)*16  -> col = l&15, K = (l>>4)*16+j.
    {
        int r_ = tid;                 // 0..255: gate g = r_>>6, unit u = r_&63
        int g = r_ >> 6, u = r_ & 63;
        const float* wrow = W_hh + r_ * 64;
        float m = 0.f;
        for (int k = 0; k < 64; ++k) m = fmaxf(m, fabsf(wrow[k]));
        float inv = (m > 0.f) ? 127.0f / m : 0.f;
        scl[r_] = m * (1.0f / 16129.0f);      // m / 127^2 (dequant factor)
        char* dst = wq8 + (g * 4 + (u >> 4)) * 1024 + (u & 15) * 16;
        for (int k = 0; k < 64; ++k) {
            int q8 = (int)rintf(wrow[k] * inv);
            dst[(k >> 4) * 256 + (k & 15)] = (char)q8;
        }
    }
    __syncthreads();

    // ---- B fragments + per-lane constants -> registers ----
    const int u0 = w * 16 + col;      // this lane's unit (cols of all 4 tiles)
    i32x4 Bq[4];
    float dqs[4], wih_s[4], bxc[4];
    i32x4 zeroi = {0, 0, 0, 0};
    #pragma unroll
    for (int gg = 0; gg < 4; ++gg) {
        int off = ((gg * 4 + w) * 4 + (lane >> 4)) * 256 + (lane & 15) * 16;
        Bq[gg] = *(const i32x4*)&wq8[off];
        asm volatile("" : "+v"(Bq[gg]));
        float scg = (gg == 2) ? -2.0f * L2E : -L2E;
        dqs[gg]   = scl[gg * 64 + u0] * scg;   // scg * rowmax / 127^2
        wih_s[gg] = W_ih[gg * HID + u0] * scg;
        bxc[gg]   = (b_ih[gg * HID + u0] + b_hh[gg * HID + u0]) * scg;
    }
    __syncthreads();   // all waves done READING staging; smem may be reused now

    // zero BOTH h buffers (h0 = 0): 2 x 256 B
    if (tid < 128) ((int*)smem)[tid] = 0;

    float cc = 0.f, hl = 0.f;

    // invariant LDS byte coords (compact 4-row exchange, i8):
    // read: lane l -> K-chunk = l>>4 (units (l>>4)*16..+15), aliased row
    //        (l>>2)&3 (valid for A-rows 4q; other lanes read garbage rows,
    //        D rows != 4q never read). 16B aligned, 2-way bank + broadcast.
    const int ard = (lane >> 4) * 64 + ((lane >> 2) & 3) * 16;
    // write: h(batch quad, unit u0) -> byte (u0>>4)*64 + quad*16 + (u0&15)
    const int hwr = w * 64 + quad * 16 + col;

    const float* xbase = x + (size_t)row0 * T_STEPS;

    // prime x prefetch for chunk 0 (loads issue here, consumed at tc=0)
    float pf0, pf1;
    {
        const float* src = xbase + (size_t)w * T_STEPS;
        pf0 = src[lane];
        pf1 = src[lane + 64];
    }
    __syncthreads();   // hbuf zeroed

    auto step = [&](auto cur_c, float xv) __attribute__((always_inline)) {
        constexpr int CUR = decltype(cur_c)::value;
        constexpr int NXT = CUR ^ 1;

        // ---- single A-frag read: K=64 i8 in one b128 ----
        i32x4 A8 = *(const i32x4*)&hbuf[CUR][ard];

        // ---- 4 MFMAs: all 4 gates, units 16w..16w+15, rows {0,4,8,12} ----
        i32x4 ai = __builtin_amdgcn_mfma_i32_16x16x64_i8(A8, Bq[0], zeroi, 0, 0, 0);
        i32x4 af = __builtin_amdgcn_mfma_i32_16x16x64_i8(A8, Bq[1], zeroi, 0, 0, 0);
        i32x4 ag = __builtin_amdgcn_mfma_i32_16x16x64_i8(A8, Bq[2], zeroi, 0, 0, 0);
        i32x4 ao = __builtin_amdgcn_mfma_i32_16x16x64_i8(A8, Bq[3], zeroi, 0, 0, 0);

        // xv-terms compute during MFMA (independent)
        float bx0 = fmaf(xv, wih_s[0], bxc[0]);
        float bx1 = fmaf(xv, wih_s[1], bxc[1]);
        float bx2 = fmaf(xv, wih_s[2], bxc[2]);
        float bx3 = fmaf(xv, wih_s[3], bxc[3]);

        // ---- fused update: quad q -> D-row 4q (reg0), ALL 64 lanes active ----
        {
            // dequant + pre-scaled arg in one fma per gate
            float a0 = fmaf((float)ai[0], dqs[0], bx0);
            float a1 = fmaf((float)af[0], dqs[1], bx1);
            float a2 = fmaf((float)ag[0], dqs[2], bx2);
            float a3 = fmaf((float)ao[0], dqs[3], bx3);
            float ig = __builtin_amdgcn_rcpf(1.0f + __builtin_amdgcn_exp2f(a0));
            float fg = __builtin_amdgcn_rcpf(1.0f + __builtin_amdgcn_exp2f(a1));
            float gv = fmaf(2.0f, __builtin_amdgcn_rcpf(1.0f + __builtin_amdgcn_exp2f(a2)), -1.0f);
            float og = __builtin_amdgcn_rcpf(1.0f + __builtin_amdgcn_exp2f(a3));
            cc = fmaf(fg, cc, ig * gv);
            float ec = __builtin_amdgcn_exp2f(-2.8853900817779268f * cc);
            float th = fmaf(2.0f, __builtin_amdgcn_rcpf(1.0f + ec), -1.0f);
            hl = og * th;
            // h -> i8 at fixed scale 127 (|h| < 1); RNE
            int hq = (int)rintf(hl * 127.0f);
            hbuf[NXT][hwr] = (char)hq;
        }
        __syncthreads();   // new h-frags visible (single barrier per step)
    };

    #pragma unroll 1
    for (int tc = 0; tc < T_STEPS; tc += 2) {
        const int tl = tc & (XCH - 1);
        if (tl == 0) {
            // boundary: commit prefetched chunk to LDS, then issue next loads
            xlds[w][lane]      = pf0;
            xlds[w][lane + 64] = pf1;
            __syncthreads();
            int nc = (tc + XCH < T_STEPS) ? (tc + XCH) : tc;  // clamp; tail unused
            const float* src = xbase + (size_t)w * T_STEPS + nc;
            pf0 = src[lane];
            pf1 = src[lane + 64];
        }
        // hoist both steps' x reads (issue with/before A-read; consumed late)
        float xv0 = xlds[quad][tl];
        float xv1 = xlds[quad][tl + 1];
        step(std::integral_constant<int, 0>{}, xv0);  // reads hbuf[0], writes hbuf[1]
        step(std::integral_constant<int, 1>{}, xv1);  // reads hbuf[1], writes hbuf[0]
    }

    // ---- epilogue: gather h, fc1 (relu) + fc2 (h kept fp32 in registers) ----
    hf[quad][u0] = hl;   // (row quad, unit 16w+col): 4x64 values, all lanes
    __syncthreads();

    if (w < ROWS) {
        // thread -> (row = w, unit = lane)
        float s = fc1_b[lane];
        const float4* wrow = (const float4*)(fc1_w + lane * HID);
        #pragma unroll
        for (int j4 = 0; j4 < HID / 4; ++j4) {
            float4 wv = wrow[j4];
            s = fmaf(hf[w][j4 * 4 + 0], wv.x, s);
            s = fmaf(hf[w][j4 * 4 + 1], wv.y, s);
            s = fmaf(hf[w][j4 * 4 + 2], wv.z, s);
            s = fmaf(hf[w][j4 * 4 + 3], wv.w, s);
        }
        r1buf[w][lane] = fmaxf(s, 0.0f);
    }
    __syncthreads();

    if (tid < ROWS * NCLS) {
        int m = tid / NCLS, cls = tid % NCLS;
        float s = fc2_b[cls];
        const float* w2 = fc2_w + cls * HID;
        #pragma unroll
        for (int j = 0; j < HID; ++j) s = fmaf(r1buf[m][j], w2[j], s);
        out[(size_t)(row0 + m) * NCLS + cls] = s;
    }
}

extern "C" void kernel_launch(void* const* d_in, const int* in_sizes, int n_in,
                              void* d_out, int out_size, void* d_ws, size_t ws_size,
                              hipStream_t stream) {
    const float* x     = (const float*)d_in[0];
    const float* W_ih  = (const float*)d_in[1];
    const float* W_hh  = (const float*)d_in[2];
    const float* b_ih  = (const float*)d_in[3];
    const float* b_hh  = (const float*)d_in[4];
    const float* fc1_w = (const float*)d_in[5];
    const float* fc1_b = (const float*)d_in[6];
    const float* fc2_w = (const float*)d_in[7];
    const float* fc2_b = (const float*)d_in[8];
    float* out = (float*)d_out;

    dim3 grid(256);   // 1024 rows / 4 rows per block -> 1 block per CU
    dim3 block(256);  // 4 waves (1 per SIMD)
    lstm_mfma_kernel<<<grid, block, 0, stream>>>(x, W_ih, W_hh, b_ih, b_hh,
                                                 fc1_w, fc1_b, fc2_w, fc2_b, out);
}

// Round 14
// 490.421 us; speedup vs baseline: 1.1211x; 1.0371x over previous
//
#include <hip/hip_runtime.h>
#include <type_traits>

// LSTMNet: B=1024, T=2048, H=64, NC=10, input_size=1.
// R26: R25 (i8 K=64, 477us rocprof - best) + chain surgery (single change):
//  - magic-constant i8 convert: t0 = fmaf(254*og, rc, -127*og) (=127*og*th,
//    muls off-chain) then y = t0 + 12582912.0f (1.5*2^23): RNE integer in
//    low mantissa byte, two's complement for negatives. Replaces
//    th-fma -> mul(og) -> mul(127) -> rndne -> cvt (5 dep ops) with 2.
//  - ccs pre-scale (R17 identity, now isolated): ccs = -2L2E*c; g-gate
//    gvs = fmaf(-4L2E, r2, 2L2E); ec = exp2(ccs) directly (saves dep mul).
//  Chain: 12 -> 9 dependent ops (~15-20cy off L=560).
//  f32 hl for epilogue computed off-path (only last iteration's value used).
// R25 verified: absmax 9.77e-4 (i8-h recurrence precision OK), conflicts
// 2048 (~zero), MfmaUtil 11.9 (4 MFMAs). L model: 560cy = exchange ~210
// (write+barrier+read) + MFMA ~140 (issue+last-result latency) + chain ~100
// + residual ~110. MFMA count minimal (N*K/wave-step = 4096, i8 supplies
// 1024/MFMA); exchange structurally cross-wave (A-chunk from other waves).
// Structure: 256 blocks x 4 waves, ROWS=4, quad q = batch row q -> D-row 4q
// reg0, fused update, 1 barrier/step, waves_per_eu(1,1), x-prefetch.

#define T_STEPS 2048
#define HID 64
#define NCLS 10
#define XCH 128   // x chunk length (steps)
#define ROWS 4    // batch rows per block

typedef int   i32x4 __attribute__((ext_vector_type(4)));
typedef float f32x4 __attribute__((ext_vector_type(4)));

__global__ __attribute__((amdgpu_flat_work_group_size(256, 256),
                          amdgpu_waves_per_eu(1, 1)))
void lstm_mfma_kernel(
    const float* __restrict__ x,      // [B, 1, T]
    const float* __restrict__ W_ih,   // [256, 1]
    const float* __restrict__ W_hh,   // [256, 64]
    const float* __restrict__ b_ih,   // [256]
    const float* __restrict__ b_hh,   // [256]
    const float* __restrict__ fc1_w,  // [64, 64]
    const float* __restrict__ fc1_b,  // [64]
    const float* __restrict__ fc2_w,  // [10, 64]
    const float* __restrict__ fc2_b,  // [10]
    float* __restrict__ out)          // [B, 10]
{
    const int tid  = threadIdx.x;
    const int lane = tid & 63;
    const int w    = tid >> 6;        // wave id = unit-chunk owner
    const int quad = lane >> 4;       // = batch row within block (D-row 4*quad)
    const int col  = lane & 15;
    const int row0 = blockIdx.x * ROWS;

    const float L2E = 1.4426950408889634f;

    // ---- LDS union: 17KB staging (dead after B-frag load) overlaps runtime ----
    __shared__ __align__(16) char smem[32768];
    char*  wq8 = smem;                        // staging Wq [0, 16384)
    float* scl = (float*)(smem + 16384);      // per-row m/127^2 [16384,17408)
    // runtime (valid only after the staging->register handoff sync):
    char  (*hbuf)[256]      = (char(*)[256])smem;               //  512 B
    float (*xlds)[XCH + 4]  = (float(*)[XCH + 4])(smem + 512);  // 2112 B
    float (*hf)[HID + 1]    = (float(*)[HID + 1])(smem + 2624); // 1040 B
    float (*r1buf)[HID + 1] = (float(*)[HID + 1])(smem + 3664); // 1040 B

    // ---- stage: W_hh -> per-row i8 (row = gate-major 0..255, one/thread) ----
    // Wq layout: off = t_*1024 + kc*256 + n*16 + j
    //   t_ = g*4 + (u>>4) (16x16 col-tile), kc = k>>4, n = u&15, j = k&15.
    {
        int r_ = tid;                 // 0..255: gate g = r_>>6, unit u = r_&63
        int g = r_ >> 6, u = r_ & 63;
        const float* wrow = W_hh + r_ * 64;
        float m = 0.f;
        for (int k = 0; k < 64; ++k) m = fmaxf(m, fabsf(wrow[k]));
        float inv = (m > 0.f) ? 127.0f / m : 0.f;
        scl[r_] = m * (1.0f / 16129.0f);      // m / 127^2 (dequant factor)
        char* dst = wq8 + (g * 4 + (u >> 4)) * 1024 + (u & 15) * 16;
        for (int k = 0; k < 64; ++k) {
            int q8 = (int)rintf(wrow[k] * inv);
            dst[(k >> 4) * 256 + (k & 15)] = (char)q8;
        }
    }
    __syncthreads();

    // ---- B fragments + per-lane constants -> registers ----
    const int u0 = w * 16 + col;      // this lane's unit (cols of all 4 tiles)
    i32x4 Bq[4];
    float dqs[4], wih_s[4], bxc[4];
    i32x4 zeroi = {0, 0, 0, 0};
    #pragma unroll
    for (int gg = 0; gg < 4; ++gg) {
        int off = ((gg * 4 + w) * 4 + (lane >> 4)) * 256 + (lane & 15) * 16;
        Bq[gg] = *(const i32x4*)&wq8[off];
        asm volatile("" : "+v"(Bq[gg]));
        float scg = (gg == 2) ? -2.0f * L2E : -L2E;
        dqs[gg]   = scl[gg * 64 + u0] * scg;   // scg * rowmax / 127^2
        wih_s[gg] = W_ih[gg * HID + u0] * scg;
        bxc[gg]   = (b_ih[gg * HID + u0] + b_hh[gg * HID + u0]) * scg;
    }
    __syncthreads();   // all waves done READING staging; smem may be reused now

    // zero BOTH h buffers (h0 = 0): 2 x 256 B
    if (tid < 128) ((int*)smem)[tid] = 0;

    float ccs = 0.f, hl = 0.f;   // ccs = -2log2e * c (pre-scaled cell state)

    // invariant LDS byte coords (compact 4-row exchange, i8):
    // read: lane l -> K-chunk = l>>4, aliased row (l>>2)&3 (valid for
    //        A-rows 4q; garbage D rows never read). 16B aligned.
    const int ard = (lane >> 4) * 64 + ((lane >> 2) & 3) * 16;
    // write: h(batch quad, unit u0) -> byte (u0>>4)*64 + quad*16 + (u0&15)
    const int hwr = w * 64 + quad * 16 + col;

    const float* xbase = x + (size_t)row0 * T_STEPS;

    // prime x prefetch for chunk 0 (loads issue here, consumed at tc=0)
    float pf0, pf1;
    {
        const float* src = xbase + (size_t)w * T_STEPS;
        pf0 = src[lane];
        pf1 = src[lane + 64];
    }
    __syncthreads();   // hbuf zeroed

    auto step = [&](auto cur_c, float xv) __attribute__((always_inline)) {
        constexpr int CUR = decltype(cur_c)::value;
        constexpr int NXT = CUR ^ 1;

        // ---- single A-frag read: K=64 i8 in one b128 ----
        i32x4 A8 = *(const i32x4*)&hbuf[CUR][ard];

        // ---- 4 MFMAs: all 4 gates, units 16w..16w+15, rows {0,4,8,12} ----
        i32x4 ai = __builtin_amdgcn_mfma_i32_16x16x64_i8(A8, Bq[0], zeroi, 0, 0, 0);
        i32x4 af = __builtin_amdgcn_mfma_i32_16x16x64_i8(A8, Bq[1], zeroi, 0, 0, 0);
        i32x4 ag = __builtin_amdgcn_mfma_i32_16x16x64_i8(A8, Bq[2], zeroi, 0, 0, 0);
        i32x4 ao = __builtin_amdgcn_mfma_i32_16x16x64_i8(A8, Bq[3], zeroi, 0, 0, 0);

        // xv-terms compute during MFMA (independent)
        float bx0 = fmaf(xv, wih_s[0], bxc[0]);
        float bx1 = fmaf(xv, wih_s[1], bxc[1]);
        float bx2 = fmaf(xv, wih_s[2], bxc[2]);
        float bx3 = fmaf(xv, wih_s[3], bxc[3]);

        // ---- fused update: quad q -> D-row 4q (reg0), ALL 64 lanes active ----
        {
            // dequant + pre-scaled arg in one fma per gate
            // (i,f,o hold -L2E*a; g holds -2L2E*a)
            float a0 = fmaf((float)ai[0], dqs[0], bx0);
            float a1 = fmaf((float)af[0], dqs[1], bx1);
            float a2 = fmaf((float)ag[0], dqs[2], bx2);
            float a3 = fmaf((float)ao[0], dqs[3], bx3);
            float ig = __builtin_amdgcn_rcpf(1.0f + __builtin_amdgcn_exp2f(a0));
            float fg = __builtin_amdgcn_rcpf(1.0f + __builtin_amdgcn_exp2f(a1));
            // g-gate pre-scaled: gvs = -2L2E*tanh = fmaf(-4L2E, r2, 2L2E)
            float r2 = __builtin_amdgcn_rcpf(1.0f + __builtin_amdgcn_exp2f(a2));
            float gvs = fmaf(-5.7707801635558536f, r2, 2.8853900817779268f);
            float og = __builtin_amdgcn_rcpf(1.0f + __builtin_amdgcn_exp2f(a3));
            float igvs = ig * gvs;                 // = -2L2E * i*g~
            ccs = fmaf(fg, ccs, igvs);             // ccs = -2L2E * c
            float ec = __builtin_amdgcn_exp2f(ccs);
            float rc = __builtin_amdgcn_rcpf(1.0f + ec);  // tanh(c) = 2rc-1
            // i8 convert, magic-constant RNE (og-muls off the dependent chain)
            float og254 = 254.0f * og, ogn127 = -127.0f * og;
            float t0 = fmaf(og254, rc, ogn127);    // = 127 * og * tanh(c)
            float y  = t0 + 12582912.0f;           // 1.5*2^23: RNE int in low byte
            hbuf[NXT][hwr] = (char)__builtin_bit_cast(int, y);
            // f32 h for epilogue (off the critical path; used after last step)
            hl = fmaf(og + og, rc, -og);           // og * (2rc - 1)
        }
        __syncthreads();   // new h-frags visible (single barrier per step)
    };

    #pragma unroll 1
    for (int tc = 0; tc < T_STEPS; tc += 2) {
        const int tl = tc & (XCH - 1);
        if (tl == 0) {
            // boundary: commit prefetched chunk to LDS, then issue next loads
            xlds[w][lane]      = pf0;
            xlds[w][lane + 64] = pf1;
            __syncthreads();
            int nc = (tc + XCH < T_STEPS) ? (tc + XCH) : tc;  // clamp; tail unused
            const float* src = xbase + (size_t)w * T_STEPS + nc;
            pf0 = src[lane];
            pf1 = src[lane + 64];
        }
        // hoist both steps' x reads (issue with/before A-read; consumed late)
        float xv0 = xlds[quad][tl];
        float xv1 = xlds[quad][tl + 1];
        step(std::integral_constant<int, 0>{}, xv0);  // reads hbuf[0], writes hbuf[1]
        step(std::integral_constant<int, 1>{}, xv1);  // reads hbuf[1], writes hbuf[0]
    }

    // ---- epilogue: gather h, fc1 (relu) + fc2 (h kept fp32 in registers) ----
    hf[quad][u0] = hl;   // (row quad, unit 16w+col): 4x64 values, all lanes
    __syncthreads();

    if (w < ROWS) {
        // thread -> (row = w, unit = lane)
        float s = fc1_b[lane];
        const float4* wrow = (const float4*)(fc1_w + lane * HID);
        #pragma unroll
        for (int j4 = 0; j4 < HID / 4; ++j4) {
            float4 wv = wrow[j4];
            s = fmaf(hf[w][j4 * 4 + 0], wv.x, s);
            s = fmaf(hf[w][j4 * 4 + 1], wv.y, s);
            s = fmaf(hf[w][j4 * 4 + 2], wv.z, s);
            s = fmaf(hf[w][j4 * 4 + 3], wv.w, s);
        }
        r1buf[w][lane] = fmaxf(s, 0.0f);
    }
    __syncthreads();

    if (tid < ROWS * NCLS) {
        int m = tid / NCLS, cls = tid % NCLS;
        float s = fc2_b[cls];
        const float* w2 = fc2_w + cls * HID;
        #pragma unroll
        for (int j = 0; j < HID; ++j) s = fmaf(r1buf[m][j], w2[j], s);
        out[(size_t)(row0 + m) * NCLS + cls] = s;
    }
}

extern "C" void kernel_launch(void* const* d_in, const int* in_sizes, int n_in,
                              void* d_out, int out_size, void* d_ws, size_t ws_size,
                              hipStream_t stream) {
    const float* x     = (const float*)d_in[0];
    const float* W_ih  = (const float*)d_in[1];
    const float* W_hh  = (const float*)d_in[2];
    const float* b_ih  = (const float*)d_in[3];
    const float* b_hh  = (const float*)d_in[4];
    const float* fc1_w = (const float*)d_in[5];
    const float* fc1_b = (const float*)d_in[6];
    const float* fc2_w = (const float*)d_in[7];
    const float* fc2_b = (const float*)d_in[8];
    float* out = (float*)d_out;

    dim3 grid(256);   // 1024 rows / 4 rows per block -> 1 block per CU
    dim3 block(256);  // 4 waves (1 per SIMD)
    lstm_mfma_kernel<<<grid, block, 0, stream>>>(x, W_ih, W_hh, b_ih, b_hh,
                                                 fc1_w, fc1_b, fc2_w, fc2_b, out);
}